// Round 3
// baseline (1441.825 us; speedup 1.0000x reference)
//
#include <hip/hip_runtime.h>

// Sparse conv block, output-major + pre-summed bins:
//   invert rulebook -> per-(k,o): ONE gather index (single input, or pre-summed
//   aux row for multi-input bins) -> gather-only MFMA conv, software-pipelined,
//   exactly one A-gather + 8 MFMA per k, plain stores, fused BN stats
//   -> BatchNorm -> ReLU.                          MI355X / gfx950.

#define N_VOX   100000
#define NPAD    100096                  // multiple of 64
#define C_INCH  64
#define C_OUTCH 64
#define K3      27
#define M_PAIRS 40000
#define NPAIRS  (K3 * M_PAIRS)          // 1,080,000
#define BN_EPS  1e-5f
#define NBINS   (K3 * NPAD)             // 2,702,592
#define AUXMAX  184320                  // expected ~166k cnt>=2 bins
#define OVMAX   65536                   // expected ~23k slot>=2 extras

// ---- workspace layout (bytes), total 62,936,896 -----------------------------
#define OFF_WT     0u                           // bf16 Wt[k][c][i]
#define OFF_STATS  221184u                      // f32[128]
#define OFF_CTRS   221696u                      // auxcnt @+0, ovcnt @+4
#define OFF_CNT    221760u                      // u8 cnt[NBINS] (packed in u32)
#define OFF_GINX   2924352u                     // int ginx[NBINS], -1 = empty
#define OFF_IN1    13734720u                    // int in1[NBINS]
#define OFF_LIST   24545088u                    // int2 list[AUXMAX]
#define OFF_OV     26019648u                    // int2 ov[OVMAX]
#define OFF_XB     26543936u                    // bf16 rows[N_VOX + AUXMAX][64]
#define WS_NEED    ((size_t)OFF_XB + (size_t)(N_VOX + AUXMAX) * 128u)

typedef __attribute__((ext_vector_type(8))) short bf16x8;
typedef __attribute__((ext_vector_type(4))) float f32x4;

__device__ __forceinline__ short f2bf(float f) {
  unsigned u = __builtin_bit_cast(unsigned, f);
  u += 0x7FFFu + ((u >> 16) & 1u);
  return (short)(u >> 16);
}
__device__ __forceinline__ float bf2f(short s) {
  unsigned u = ((unsigned)(unsigned short)s) << 16;
  return __builtin_bit_cast(float, u);
}

// ---- W[k][i][c] (f32) -> Wt[k][c][i] (bf16) ---------------------------------
__global__ __launch_bounds__(256) void wconv_kernel(const float* __restrict__ W,
                                                    short* __restrict__ wt) {
  int id = blockIdx.x * 256 + threadIdx.x;
  if (id >= K3 * 4096) return;
  int k = id >> 12, rem = id & 4095, c = rem >> 6, i = rem & 63;
  wt[id] = f2bf(W[(k << 12) + (i << 6) + c]);
}

// ---- x (f32) -> xb (bf16) ---------------------------------------------------
__global__ __launch_bounds__(256) void xconv_kernel(const float* __restrict__ x,
                                                    short* __restrict__ xb) {
  int id = blockIdx.x * 256 + threadIdx.x;
  if (id >= N_VOX * 8) return;
  float4 lo = ((const float4*)x)[id * 2];
  float4 hi = ((const float4*)x)[id * 2 + 1];
  bf16x8 v;
  v[0] = f2bf(lo.x); v[1] = f2bf(lo.y); v[2] = f2bf(lo.z); v[3] = f2bf(lo.w);
  v[4] = f2bf(hi.x); v[5] = f2bf(hi.y); v[6] = f2bf(hi.z); v[7] = f2bf(hi.w);
  ((bf16x8*)xb)[id] = v;
}

// ---- invert rulebook (SoA): cnt (byte-packed atomics), ginx=slot0, in1=slot1,
//      slot>=2 -> overflow list ----------------------------------------------
__global__ __launch_bounds__(256) void build_kernel(const int* __restrict__ in_idx,
                                                    const int* __restrict__ out_idx,
                                                    unsigned* __restrict__ cnt32,
                                                    int* __restrict__ ginx,
                                                    int* __restrict__ in1,
                                                    int2* __restrict__ ov,
                                                    int* __restrict__ ctrs) {
  int id = blockIdx.x * 256 + threadIdx.x;
  if (id >= NPAIRS) return;
  int k  = id / M_PAIRS;
  int in = in_idx[id];
  int o  = out_idx[id];
  int b  = k * NPAD + o;
  unsigned sh  = (unsigned)(b & 3) * 8u;
  unsigned old = atomicAdd(&cnt32[b >> 2], 1u << sh);
  unsigned slot = (old >> sh) & 0xFFu;
  if (slot == 0u) {
    ginx[b] = in;
  } else if (slot == 1u) {
    in1[b] = in;
  } else {
    int p = atomicAdd(&ctrs[1], 1);
    if (p < OVMAX) ov[p] = make_int2((k << 17) | in, o);
  }
}

// ---- scan: bins with cnt>=2 get an aux slot; list[pos]={in0,in1};
//      ginx[b] -> N_VOX + pos ------------------------------------------------
__global__ __launch_bounds__(256) void scan_kernel(const unsigned* __restrict__ cnt32,
                                                   int* __restrict__ ginx,
                                                   const int* __restrict__ in1,
                                                   int2* __restrict__ list,
                                                   int* __restrict__ ctrs) {
  int w = blockIdx.x * 256 + threadIdx.x;        // one u32 = 4 bins
  if (w >= NBINS / 4) return;
  unsigned c4 = cnt32[w];
  if (c4 < 0x02020202u ? ((c4 & 0xFEFEFEFEu) == 0u) : false) return;  // all cnt<2 fast-out
  #pragma unroll
  for (int s = 0; s < 4; ++s) {
    unsigned c = (c4 >> (s * 8)) & 0xFFu;
    if (c >= 2u) {
      int b = w * 4 + s;
      int pos = atomicAdd(&ctrs[0], 1);
      if (pos < AUXMAX) {
        list[pos] = make_int2(ginx[b], in1[b]);
        ginx[b] = N_VOX + pos;
      }
    }
  }
}

// ---- fixup: one wave per aux slot: xb[N_VOX+i] = xb[in0] + xb[in1] ----------
__global__ __launch_bounds__(256) void fixup_kernel(short* __restrict__ xb,
                                                    const int2* __restrict__ list,
                                                    const int* __restrict__ ctrs) {
  int n = ctrs[0]; if (n > AUXMAX) n = AUXMAX;
  int wid  = (blockIdx.x * 256 + threadIdx.x) >> 6;
  int lane = threadIdx.x & 63;
  int nw   = gridDim.x * 4;
  for (int i = wid; i < n; i += nw) {
    int2 p = list[i];
    float a = bf2f(xb[(size_t)p.x * 64 + lane]);
    float b = bf2f(xb[(size_t)p.y * 64 + lane]);
    xb[(size_t)(N_VOX + i) * 64 + lane] = f2bf(a + b);
  }
}

// ---- conv: wave owns 16 out rows; exactly one gather + 8 MFMA per k;
//      depth-2 software pipeline; fused BN partial stats ----------------------
// A lane l: row=l&15, k-slots (l>>4)*8+j (+32);  B lane l: col=l&15, same slots.
// C/D: col=lane&15, row=(lane>>4)*4+reg  [round-1/2 proven].
__global__ __launch_bounds__(256) void conv_out_kernel(const short* __restrict__ xb,
                                                       const short* __restrict__ wt,
                                                       const int* __restrict__ ginx,
                                                       float* __restrict__ out,
                                                       float* __restrict__ stats) {
  __shared__ float ls[128];
  int t = threadIdx.x, wave = t >> 6, lane = t & 63;
  int g = lane >> 4, c0 = lane & 15, g8 = g * 8;
  int o = blockIdx.x * 64 + wave * 16 + c0;
  if (t < 128) ls[t] = 0.f;
  __syncthreads();

  f32x4 acc[4];
  #pragma unroll
  for (int n = 0; n < 4; ++n) { acc[n][0]=0.f; acc[n][1]=0.f; acc[n][2]=0.f; acc[n][3]=0.f; }

  // pipeline: idx for k+2 in flight, x-row for k+1 in flight
  int idxB = ginx[o];                       // k=0 (consumed as prefetch below)
  bf16x8 a0c = {0,0,0,0,0,0,0,0}, a1c = {0,0,0,0,0,0,0,0};
  if (idxB >= 0) {
    const short* xr = xb + (size_t)idxB * 64;
    a0c = *(const bf16x8*)(xr + g8);
    a1c = *(const bf16x8*)(xr + 32 + g8);
  }
  idxB = ginx[NPAD + o];                    // k=1

  for (int k = 0; k < K3; ++k) {
    int idxN = (k + 2 < K3) ? ginx[(size_t)(k + 2) * NPAD + o] : -1;
    bf16x8 a0n = {0,0,0,0,0,0,0,0}, a1n = {0,0,0,0,0,0,0,0};
    if (idxB >= 0) {
      const short* xr = xb + (size_t)idxB * 64;
      a0n = *(const bf16x8*)(xr + g8);
      a1n = *(const bf16x8*)(xr + 32 + g8);
    }
    const short* wtk = wt + k * 4096;
    #pragma unroll
    for (int n = 0; n < 4; ++n) {
      const short* wp = wtk + (n * 16 + c0) * 64 + g8;
      bf16x8 b0 = *(const bf16x8*)(wp);
      bf16x8 b1 = *(const bf16x8*)(wp + 32);
      acc[n] = __builtin_amdgcn_mfma_f32_16x16x32_bf16(a0c, b0, acc[n], 0, 0, 0);
      acc[n] = __builtin_amdgcn_mfma_f32_16x16x32_bf16(a1c, b1, acc[n], 0, 0, 0);
    }
    a0c = a0n; a1c = a1n; idxB = idxN;
  }

  // store (each out row exactly once)
  int orow = blockIdx.x * 64 + wave * 16 + (g << 2);
  #pragma unroll
  for (int j = 0; j < 4; ++j) {
    int r = orow + j;
    if (r < N_VOX) {
      float* op = out + (size_t)r * 64 + c0;
      op[0]  = acc[0][j];
      op[16] = acc[1][j];
      op[32] = acc[2][j];
      op[48] = acc[3][j];
    }
  }

  // fused BN partial stats (padding rows hold exact zeros -> contribute 0)
  #pragma unroll
  for (int n = 0; n < 4; ++n) {
    float s = 0.f, q = 0.f;
    #pragma unroll
    for (int j = 0; j < 4; ++j) { float v = acc[n][j]; s += v; q += v * v; }
    atomicAdd(&ls[n * 16 + c0], s);
    atomicAdd(&ls[64 + n * 16 + c0], q);
  }
  __syncthreads();
  if (t < 128) unsafeAtomicAdd(&stats[t], ls[t]);
}

// ---- overflow extras (slot>=2): exact fp32 dot, atomic out + stats telescope -
__global__ __launch_bounds__(256) void ov_kernel(const float* __restrict__ x,
                                                 const float* __restrict__ W,
                                                 const int2* __restrict__ ov,
                                                 const int* __restrict__ ctrs,
                                                 float* __restrict__ out,
                                                 float* __restrict__ stats) {
  int n = ctrs[1]; if (n > OVMAX) n = OVMAX;
  int wid  = (blockIdx.x * 256 + threadIdx.x) >> 6;
  int lane = threadIdx.x & 63;
  int nw   = gridDim.x * 4;
  for (int i = wid; i < n; i += nw) {
    int2 e = ov[i];
    int in = e.x & 0x1FFFF;
    int k  = e.x >> 17;
    int o  = e.y;
    const float* xr = x + (size_t)in * 64;
    const float* wp = W + (size_t)k * 4096 + lane;
    float d = 0.f;
    #pragma unroll 8
    for (int ii = 0; ii < 64; ++ii) d += xr[ii] * wp[ii * 64];
    float old = unsafeAtomicAdd(&out[(size_t)o * 64 + lane], d);
    unsafeAtomicAdd(&stats[lane], d);
    unsafeAtomicAdd(&stats[64 + lane], d * d + 2.f * d * old);
  }
}

// ---- legacy fallback: scatter conv + separate stats (if ws too small) -------
__global__ __launch_bounds__(256) void conv_kernel(const float* __restrict__ x,
                                                   const short* __restrict__ wt,
                                                   const int* __restrict__ in_idx,
                                                   const int* __restrict__ out_idx,
                                                   float* __restrict__ out) {
  __shared__ int s_in[64];
  __shared__ int s_out[64];
  int bx = blockIdx.x;
  int k = bx / (M_PAIRS / 64), base = (bx % (M_PAIRS / 64)) * 64;
  int t = threadIdx.x;
  if (t < 64)       s_in[t]       = in_idx[k * M_PAIRS + base + t];
  else if (t < 128) s_out[t - 64] = out_idx[k * M_PAIRS + base + (t - 64)];
  __syncthreads();
  int wave = t >> 6, lane = t & 63, g = lane >> 4, c0 = lane & 15;
  const float* xrow = x + (size_t)s_in[(wave << 4) + c0] * C_INCH + g * 8;
  float4 a0lo = *(const float4*)(xrow);
  float4 a0hi = *(const float4*)(xrow + 4);
  float4 a1lo = *(const float4*)(xrow + 32);
  float4 a1hi = *(const float4*)(xrow + 36);
  bf16x8 a0, a1;
  a0[0]=f2bf(a0lo.x); a0[1]=f2bf(a0lo.y); a0[2]=f2bf(a0lo.z); a0[3]=f2bf(a0lo.w);
  a0[4]=f2bf(a0hi.x); a0[5]=f2bf(a0hi.y); a0[6]=f2bf(a0hi.z); a0[7]=f2bf(a0hi.w);
  a1[0]=f2bf(a1lo.x); a1[1]=f2bf(a1lo.y); a1[2]=f2bf(a1lo.z); a1[3]=f2bf(a1lo.w);
  a1[4]=f2bf(a1hi.x); a1[5]=f2bf(a1hi.y); a1[6]=f2bf(a1hi.z); a1[7]=f2bf(a1hi.w);
  const short* wtk = wt + k * 4096;
  f32x4 acc[4];
  #pragma unroll
  for (int n = 0; n < 4; ++n) { acc[n][0]=0.f; acc[n][1]=0.f; acc[n][2]=0.f; acc[n][3]=0.f; }
  #pragma unroll
  for (int n = 0; n < 4; ++n) {
    int c = n * 16 + c0;
    bf16x8 b0 = *(const bf16x8*)(wtk + c * 64 + g * 8);
    bf16x8 b1 = *(const bf16x8*)(wtk + c * 64 + 32 + g * 8);
    acc[n] = __builtin_amdgcn_mfma_f32_16x16x32_bf16(a0, b0, acc[n], 0, 0, 0);
    acc[n] = __builtin_amdgcn_mfma_f32_16x16x32_bf16(a1, b1, acc[n], 0, 0, 0);
  }
  int rbase = (wave << 4) + ((lane >> 4) << 2);
  #pragma unroll
  for (int j = 0; j < 4; ++j) {
    size_t o2 = (size_t)s_out[rbase + j] * C_OUTCH;
    #pragma unroll
    for (int n = 0; n < 4; ++n) unsafeAtomicAdd(&out[o2 + n * 16 + c0], acc[n][j]);
  }
}

__global__ __launch_bounds__(256) void stats_kernel(const float* __restrict__ out,
                                                    float* __restrict__ stats) {
  __shared__ float s1[256], s2[256];
  int t = threadIdx.x, c = t & 63, rsub = t >> 6;
  float sum1 = 0.f, sum2 = 0.f;
  for (int r = blockIdx.x * 4 + rsub; r < N_VOX; r += gridDim.x * 4) {
    float v = out[r * 64 + c];
    sum1 += v; sum2 += v * v;
  }
  s1[t] = sum1; s2[t] = sum2;
  __syncthreads();
  if (t < 64) {
    sum1 = s1[t] + s1[t + 64] + s1[t + 128] + s1[t + 192];
    sum2 = s2[t] + s2[t + 64] + s2[t + 128] + s2[t + 192];
    unsafeAtomicAdd(&stats[c], sum1);
    unsafeAtomicAdd(&stats[64 + c], sum2);
  }
}

// ---- finalize BN + ReLU in place -------------------------------------------
__global__ __launch_bounds__(256) void norm_kernel(float* __restrict__ out,
                                                   const float* __restrict__ stats,
                                                   const float* __restrict__ gamma,
                                                   const float* __restrict__ beta) {
  int i4 = blockIdx.x * 256 + threadIdx.x;
  if (i4 >= N_VOX * (C_OUTCH / 4)) return;
  const float invN = 1.0f / (float)N_VOX;
  float4 v = ((const float4*)out)[i4];
  int c0 = (i4 << 2) & 63;
  float r[4] = {v.x, v.y, v.z, v.w};
  #pragma unroll
  for (int j = 0; j < 4; ++j) {
    int c = c0 + j;
    float mean = stats[c] * invN;
    float ex2  = stats[64 + c] * invN;
    float var  = ex2 - mean * mean;
    float scale = gamma[c] * rsqrtf(var + BN_EPS);
    float shift = beta[c] - mean * scale;
    r[j] = fmaxf(r[j] * scale + shift, 0.0f);
  }
  v.x = r[0]; v.y = r[1]; v.z = r[2]; v.w = r[3];
  ((float4*)out)[i4] = v;
}

extern "C" void kernel_launch(void* const* d_in, const int* in_sizes, int n_in,
                              void* d_out, int out_size, void* d_ws, size_t ws_size,
                              hipStream_t stream) {
  const float* x      = (const float*)d_in[0];
  const float* W      = (const float*)d_in[1];
  const float* gamma  = (const float*)d_in[2];
  const float* beta   = (const float*)d_in[3];
  const int*   in_idx = (const int*)d_in[4];
  const int*   out_idx= (const int*)d_in[5];
  float* out = (float*)d_out;

  char* ws = (char*)d_ws;
  short*    wt    = (short*)(ws + OFF_WT);
  float*    stats = (float*)(ws + OFF_STATS);
  int*      ctrs  = (int*)(ws + OFF_CTRS);
  unsigned* cnt32 = (unsigned*)(ws + OFF_CNT);
  int*      ginx  = (int*)(ws + OFF_GINX);
  int*      in1   = (int*)(ws + OFF_IN1);
  int2*     list  = (int2*)(ws + OFF_LIST);
  int2*     ov    = (int2*)(ws + OFF_OV);
  short*    xb    = (short*)(ws + OFF_XB);

  wconv_kernel<<<(K3 * 4096 + 255) / 256, 256, 0, stream>>>(W, wt);
  hipMemsetAsync(ws + OFF_STATS, 0, OFF_CNT - OFF_STATS, stream);   // stats + ctrs

  if (ws_size >= WS_NEED) {
    hipMemsetAsync(ws + OFF_CNT, 0x00, NBINS, stream);              // cnt = 0
    hipMemsetAsync(ws + OFF_GINX, 0xFF, NBINS * 4, stream);         // ginx = -1
    xconv_kernel<<<(N_VOX * 8 + 255) / 256, 256, 0, stream>>>(x, xb);
    build_kernel<<<(NPAIRS + 255) / 256, 256, 0, stream>>>(in_idx, out_idx,
                                                           cnt32, ginx, in1, ov, ctrs);
    scan_kernel<<<(NBINS / 4 + 255) / 256, 256, 0, stream>>>(cnt32, ginx, in1, list, ctrs);
    fixup_kernel<<<1024, 256, 0, stream>>>(xb, list, ctrs);
    conv_out_kernel<<<NPAD / 64, 256, 0, stream>>>(xb, wt, ginx, out, stats);
    ov_kernel<<<256, 256, 0, stream>>>(x, W, ov, ctrs, out, stats);
  } else {
    hipMemsetAsync(d_out, 0, (size_t)N_VOX * C_OUTCH * sizeof(float), stream);
    conv_kernel<<<K3 * (M_PAIRS / 64), 256, 0, stream>>>(x, wt, in_idx, out_idx, out);
    stats_kernel<<<256, 256, 0, stream>>>(out, stats);
  }

  norm_kernel<<<(N_VOX * (C_OUTCH / 4) + 255) / 256, 256, 0, stream>>>(out, stats, gamma, beta);
}

// Round 4
// 421.484 us; speedup vs baseline: 3.4208x; 3.4208x over previous
//
#include <hip/hip_runtime.h>

// Sparse conv block, output-major + pre-summed bins (round 4):
//   invert rulebook -> per-(k,o): ONE gather index (single input, or pre-summed
//   aux row) -> gather-only MFMA conv (1 gather + 8 MFMA per k, plain stores)
//   -> BN stats pass -> BN+ReLU.
// Round-4 fix: all shared counters use block-aggregated allocation (LDS count,
// one global atomic per block); stats un-fused (round-3 telescope was 587us of
// same-address atomic serialization).              MI355X / gfx950.

#define N_VOX   100000
#define NPAD    100096                  // multiple of 64
#define C_INCH  64
#define C_OUTCH 64
#define K3      27
#define M_PAIRS 40000
#define NPAIRS  (K3 * M_PAIRS)          // 1,080,000
#define BN_EPS  1e-5f
#define NBINS   (K3 * NPAD)             // 2,702,592
#define AUXMAX  184320                  // expected ~166k cnt>=2 bins
#define OVMAX   65536                   // expected ~23.6k slot>=2 extras

// ---- workspace layout (bytes) — identical to round 3 (known to fit) ---------
#define OFF_WT     0u
#define OFF_STATS  221184u
#define OFF_CTRS   221696u                      // [0]=auxcnt [1]=ovcnt
#define OFF_CNT    221760u                      // u8 cnt[NBINS] packed in u32
#define OFF_GINX   2924352u                     // int ginx[NBINS], -1 = empty
#define OFF_IN1    13734720u                    // int in1[NBINS]
#define OFF_LIST   24545088u                    // int2 list[AUXMAX]
#define OFF_OV     26019648u                    // int2 ov[OVMAX]
#define OFF_XB     26543936u                    // bf16 rows[N_VOX+AUXMAX][64]
#define WS_NEED    ((size_t)OFF_XB + (size_t)(N_VOX + AUXMAX) * 128u)

typedef __attribute__((ext_vector_type(8))) short bf16x8;
typedef __attribute__((ext_vector_type(4))) float f32x4;

__device__ __forceinline__ short f2bf(float f) {
  unsigned u = __builtin_bit_cast(unsigned, f);
  u += 0x7FFFu + ((u >> 16) & 1u);
  return (short)(u >> 16);
}
__device__ __forceinline__ float bf2f(short s) {
  unsigned u = ((unsigned)(unsigned short)s) << 16;
  return __builtin_bit_cast(float, u);
}

// ---- W[k][i][c] (f32) -> Wt[k][c][i] (bf16) ---------------------------------
__global__ __launch_bounds__(256) void wconv_kernel(const float* __restrict__ W,
                                                    short* __restrict__ wt) {
  int id = blockIdx.x * 256 + threadIdx.x;
  if (id >= K3 * 4096) return;
  int k = id >> 12, rem = id & 4095, c = rem >> 6, i = rem & 63;
  wt[id] = f2bf(W[(k << 12) + (i << 6) + c]);
}

// ---- x (f32) -> xb (bf16) ---------------------------------------------------
__global__ __launch_bounds__(256) void xconv_kernel(const float* __restrict__ x,
                                                    short* __restrict__ xb) {
  int id = blockIdx.x * 256 + threadIdx.x;
  if (id >= N_VOX * 8) return;
  float4 lo = ((const float4*)x)[id * 2];
  float4 hi = ((const float4*)x)[id * 2 + 1];
  bf16x8 v;
  v[0] = f2bf(lo.x); v[1] = f2bf(lo.y); v[2] = f2bf(lo.z); v[3] = f2bf(lo.w);
  v[4] = f2bf(hi.x); v[5] = f2bf(hi.y); v[6] = f2bf(hi.z); v[7] = f2bf(hi.w);
  ((bf16x8*)xb)[id] = v;
}

// ---- invert rulebook: cnt byte-atomics; slot0->ginx, slot1->in1,
//      slot>=2 -> ov with block-aggregated counter --------------------------
__global__ __launch_bounds__(256) void build_kernel(const int* __restrict__ in_idx,
                                                    const int* __restrict__ out_idx,
                                                    unsigned* __restrict__ cnt32,
                                                    int* __restrict__ ginx,
                                                    int* __restrict__ in1,
                                                    int2* __restrict__ ov,
                                                    int* __restrict__ ctrs) {
  __shared__ int l_cnt, l_base;
  int t = threadIdx.x;
  if (t == 0) l_cnt = 0;
  __syncthreads();
  int id = blockIdx.x * 256 + t;
  int lpos = -1;
  int2 entry;
  if (id < NPAIRS) {
    int k  = id / M_PAIRS;
    int in = in_idx[id];
    int o  = out_idx[id];
    int b  = k * NPAD + o;
    unsigned sh   = (unsigned)(b & 3) * 8u;
    unsigned old  = atomicAdd(&cnt32[b >> 2], 1u << sh);
    unsigned slot = (old >> sh) & 0xFFu;
    if (slot == 0u)      ginx[b] = in;
    else if (slot == 1u) in1[b]  = in;
    else { lpos = atomicAdd(&l_cnt, 1); entry = make_int2((k << 17) | in, o); }
  }
  __syncthreads();
  if (t == 0) l_base = (l_cnt > 0) ? atomicAdd(&ctrs[1], l_cnt) : 0;
  __syncthreads();
  if (lpos >= 0) {
    int p = l_base + lpos;
    if (p < OVMAX) ov[p] = entry;
  }
}

// ---- scan: cnt>=2 bins get aux slot (block-aggregated allocation) -----------
__global__ __launch_bounds__(256) void scan_kernel(const unsigned* __restrict__ cnt32,
                                                   int* __restrict__ ginx,
                                                   const int* __restrict__ in1,
                                                   int2* __restrict__ list,
                                                   int* __restrict__ ctrs) {
  __shared__ int l_cnt, l_base;
  int t = threadIdx.x;
  if (t == 0) l_cnt = 0;
  __syncthreads();
  int w = blockIdx.x * 256 + t;                 // one u32 word = 4 bins
  unsigned c4 = (w < NBINS / 4) ? cnt32[w] : 0u;
  int lp[4];
  #pragma unroll
  for (int s = 0; s < 4; ++s) {
    unsigned c = (c4 >> (s * 8)) & 0xFFu;
    lp[s] = (c >= 2u) ? atomicAdd(&l_cnt, 1) : -1;
  }
  __syncthreads();
  if (t == 0) l_base = (l_cnt > 0) ? atomicAdd(&ctrs[0], l_cnt) : 0;
  __syncthreads();
  int base = l_base;
  #pragma unroll
  for (int s = 0; s < 4; ++s) {
    if (lp[s] >= 0) {
      int b   = w * 4 + s;
      int pos = base + lp[s];
      if (pos < AUXMAX) {
        list[pos] = make_int2(ginx[b], in1[b]);
        ginx[b]   = N_VOX + pos;
      }
    }
  }
}

// ---- fixup: xb[N_VOX+i] = xb[in0] + xb[in1] ---------------------------------
__global__ __launch_bounds__(256) void fixup_kernel(short* __restrict__ xb,
                                                    const int2* __restrict__ list,
                                                    const int* __restrict__ ctrs) {
  int n = ctrs[0]; if (n > AUXMAX) n = AUXMAX;
  int wid  = (blockIdx.x * 256 + threadIdx.x) >> 6;
  int lane = threadIdx.x & 63;
  int nw   = gridDim.x * 4;
  for (int i = wid; i < n; i += nw) {
    int2 p = list[i];
    float a = bf2f(xb[(size_t)p.x * 64 + lane]);
    float b = bf2f(xb[(size_t)p.y * 64 + lane]);
    xb[(size_t)(N_VOX + i) * 64 + lane] = f2bf(a + b);
  }
}

// ---- conv: wave owns 16 out rows; 1 gather + 8 MFMA per k; depth-2 pipeline -
// A lane l: row=l&15, k-slots (l>>4)*8+j (+32);  B lane l: col=l&15, same slots.
// C/D: col=lane&15, row=(lane>>4)*4+reg  [rounds 1-3 proven].
__global__ __launch_bounds__(256) void conv_out_kernel(const short* __restrict__ xb,
                                                       const short* __restrict__ wt,
                                                       const int* __restrict__ ginx,
                                                       float* __restrict__ out) {
  int t = threadIdx.x, wave = t >> 6, lane = t & 63;
  int g = lane >> 4, c0 = lane & 15, g8 = g * 8;
  int o = blockIdx.x * 64 + wave * 16 + c0;

  f32x4 acc[4];
  #pragma unroll
  for (int n = 0; n < 4; ++n) { acc[n][0]=0.f; acc[n][1]=0.f; acc[n][2]=0.f; acc[n][3]=0.f; }

  // pipeline: idx for k+2 in flight, x-row for k+1 in flight
  int idxB = ginx[o];                       // k=0
  bf16x8 a0c = {0,0,0,0,0,0,0,0}, a1c = {0,0,0,0,0,0,0,0};
  if (idxB >= 0) {
    const short* xr = xb + (size_t)idxB * 64;
    a0c = *(const bf16x8*)(xr + g8);
    a1c = *(const bf16x8*)(xr + 32 + g8);
  }
  idxB = ginx[NPAD + o];                    // k=1

  for (int k = 0; k < K3; ++k) {
    int idxN = (k + 2 < K3) ? ginx[(size_t)(k + 2) * NPAD + o] : -1;
    bf16x8 a0n = {0,0,0,0,0,0,0,0}, a1n = {0,0,0,0,0,0,0,0};
    if (idxB >= 0) {
      const short* xr = xb + (size_t)idxB * 64;
      a0n = *(const bf16x8*)(xr + g8);
      a1n = *(const bf16x8*)(xr + 32 + g8);
    }
    const short* wtk = wt + k * 4096;
    #pragma unroll
    for (int n = 0; n < 4; ++n) {
      const short* wp = wtk + (n * 16 + c0) * 64 + g8;
      bf16x8 b0 = *(const bf16x8*)(wp);
      bf16x8 b1 = *(const bf16x8*)(wp + 32);
      acc[n] = __builtin_amdgcn_mfma_f32_16x16x32_bf16(a0c, b0, acc[n], 0, 0, 0);
      acc[n] = __builtin_amdgcn_mfma_f32_16x16x32_bf16(a1c, b1, acc[n], 0, 0, 0);
    }
    a0c = a0n; a1c = a1n; idxB = idxN;
  }

  int orow = blockIdx.x * 64 + wave * 16 + (g << 2);
  #pragma unroll
  for (int j = 0; j < 4; ++j) {
    int r = orow + j;
    if (r < N_VOX) {
      float* op = out + (size_t)r * 64 + c0;
      op[0]  = acc[0][j];
      op[16] = acc[1][j];
      op[32] = acc[2][j];
      op[48] = acc[3][j];
    }
  }
}

// ---- overflow extras (slot>=2): exact fp32 dot, atomic add to out only ------
__global__ __launch_bounds__(256) void ov_kernel(const float* __restrict__ x,
                                                 const float* __restrict__ W,
                                                 const int2* __restrict__ ov,
                                                 const int* __restrict__ ctrs,
                                                 float* __restrict__ out) {
  int n = ctrs[1]; if (n > OVMAX) n = OVMAX;
  int wid  = (blockIdx.x * 256 + threadIdx.x) >> 6;
  int lane = threadIdx.x & 63;
  int nw   = gridDim.x * 4;
  for (int i = wid; i < n; i += nw) {
    int2 e = ov[i];
    int in = e.x & 0x1FFFF;
    int k  = e.x >> 17;
    int o  = e.y;
    const float* xr = x + (size_t)in * 64;
    const float* wp = W + (size_t)k * 4096 + lane;
    float d = 0.f;
    #pragma unroll 8
    for (int ii = 0; ii < 64; ++ii) d += xr[ii] * wp[ii * 64];
    unsafeAtomicAdd(&out[(size_t)o * 64 + lane], d);
  }
}

// ---- legacy fallback: scatter conv (if ws too small) ------------------------
__global__ __launch_bounds__(256) void conv_kernel(const float* __restrict__ x,
                                                   const short* __restrict__ wt,
                                                   const int* __restrict__ in_idx,
                                                   const int* __restrict__ out_idx,
                                                   float* __restrict__ out) {
  __shared__ int s_in[64];
  __shared__ int s_out[64];
  int bx = blockIdx.x;
  int k = bx / (M_PAIRS / 64), base = (bx % (M_PAIRS / 64)) * 64;
  int t = threadIdx.x;
  if (t < 64)       s_in[t]       = in_idx[k * M_PAIRS + base + t];
  else if (t < 128) s_out[t - 64] = out_idx[k * M_PAIRS + base + (t - 64)];
  __syncthreads();
  int wave = t >> 6, lane = t & 63, g = lane >> 4, c0 = lane & 15;
  const float* xrow = x + (size_t)s_in[(wave << 4) + c0] * C_INCH + g * 8;
  float4 a0lo = *(const float4*)(xrow);
  float4 a0hi = *(const float4*)(xrow + 4);
  float4 a1lo = *(const float4*)(xrow + 32);
  float4 a1hi = *(const float4*)(xrow + 36);
  bf16x8 a0, a1;
  a0[0]=f2bf(a0lo.x); a0[1]=f2bf(a0lo.y); a0[2]=f2bf(a0lo.z); a0[3]=f2bf(a0lo.w);
  a0[4]=f2bf(a0hi.x); a0[5]=f2bf(a0hi.y); a0[6]=f2bf(a0hi.z); a0[7]=f2bf(a0hi.w);
  a1[0]=f2bf(a1lo.x); a1[1]=f2bf(a1lo.y); a1[2]=f2bf(a1lo.z); a1[3]=f2bf(a1lo.w);
  a1[4]=f2bf(a1hi.x); a1[5]=f2bf(a1hi.y); a1[6]=f2bf(a1hi.z); a1[7]=f2bf(a1hi.w);
  const short* wtk = wt + k * 4096;
  f32x4 acc[4];
  #pragma unroll
  for (int n = 0; n < 4; ++n) { acc[n][0]=0.f; acc[n][1]=0.f; acc[n][2]=0.f; acc[n][3]=0.f; }
  #pragma unroll
  for (int n = 0; n < 4; ++n) {
    int c = n * 16 + c0;
    bf16x8 b0 = *(const bf16x8*)(wtk + c * 64 + g * 8);
    bf16x8 b1 = *(const bf16x8*)(wtk + c * 64 + 32 + g * 8);
    acc[n] = __builtin_amdgcn_mfma_f32_16x16x32_bf16(a0, b0, acc[n], 0, 0, 0);
    acc[n] = __builtin_amdgcn_mfma_f32_16x16x32_bf16(a1, b1, acc[n], 0, 0, 0);
  }
  int rbase = (wave << 4) + ((lane >> 4) << 2);
  #pragma unroll
  for (int j = 0; j < 4; ++j) {
    size_t o2 = (size_t)s_out[rbase + j] * C_OUTCH;
    #pragma unroll
    for (int n = 0; n < 4; ++n) unsafeAtomicAdd(&out[o2 + n * 16 + c0], acc[n][j]);
  }
}

// ---- per-channel sum / sum-of-squares --------------------------------------
__global__ __launch_bounds__(256) void stats_kernel(const float* __restrict__ out,
                                                    float* __restrict__ stats) {
  __shared__ float s1[256], s2[256];
  int t = threadIdx.x, c = t & 63, rsub = t >> 6;
  float sum1 = 0.f, sum2 = 0.f;
  for (int r = blockIdx.x * 4 + rsub; r < N_VOX; r += gridDim.x * 4) {
    float v = out[r * 64 + c];
    sum1 += v; sum2 += v * v;
  }
  s1[t] = sum1; s2[t] = sum2;
  __syncthreads();
  if (t < 64) {
    sum1 = s1[t] + s1[t + 64] + s1[t + 128] + s1[t + 192];
    sum2 = s2[t] + s2[t + 64] + s2[t + 128] + s2[t + 192];
    unsafeAtomicAdd(&stats[c], sum1);
    unsafeAtomicAdd(&stats[64 + c], sum2);
  }
}

// ---- finalize BN + ReLU in place -------------------------------------------
__global__ __launch_bounds__(256) void norm_kernel(float* __restrict__ out,
                                                   const float* __restrict__ stats,
                                                   const float* __restrict__ gamma,
                                                   const float* __restrict__ beta) {
  int i4 = blockIdx.x * 256 + threadIdx.x;
  if (i4 >= N_VOX * (C_OUTCH / 4)) return;
  const float invN = 1.0f / (float)N_VOX;
  float4 v = ((const float4*)out)[i4];
  int c0 = (i4 << 2) & 63;
  float r[4] = {v.x, v.y, v.z, v.w};
  #pragma unroll
  for (int j = 0; j < 4; ++j) {
    int c = c0 + j;
    float mean = stats[c] * invN;
    float ex2  = stats[64 + c] * invN;
    float var  = ex2 - mean * mean;
    float scale = gamma[c] * rsqrtf(var + BN_EPS);
    float shift = beta[c] - mean * scale;
    r[j] = fmaxf(r[j] * scale + shift, 0.0f);
  }
  v.x = r[0]; v.y = r[1]; v.z = r[2]; v.w = r[3];
  ((float4*)out)[i4] = v;
}

extern "C" void kernel_launch(void* const* d_in, const int* in_sizes, int n_in,
                              void* d_out, int out_size, void* d_ws, size_t ws_size,
                              hipStream_t stream) {
  const float* x      = (const float*)d_in[0];
  const float* W      = (const float*)d_in[1];
  const float* gamma  = (const float*)d_in[2];
  const float* beta   = (const float*)d_in[3];
  const int*   in_idx = (const int*)d_in[4];
  const int*   out_idx= (const int*)d_in[5];
  float* out = (float*)d_out;

  char* ws = (char*)d_ws;
  short*    wt    = (short*)(ws + OFF_WT);
  float*    stats = (float*)(ws + OFF_STATS);
  int*      ctrs  = (int*)(ws + OFF_CTRS);
  unsigned* cnt32 = (unsigned*)(ws + OFF_CNT);
  int*      ginx  = (int*)(ws + OFF_GINX);
  int*      in1   = (int*)(ws + OFF_IN1);
  int2*     list  = (int2*)(ws + OFF_LIST);
  int2*     ov    = (int2*)(ws + OFF_OV);
  short*    xb    = (short*)(ws + OFF_XB);

  wconv_kernel<<<(K3 * 4096 + 255) / 256, 256, 0, stream>>>(W, wt);
  hipMemsetAsync(ws + OFF_STATS, 0, OFF_CNT - OFF_STATS, stream);   // stats + ctrs

  if (ws_size >= WS_NEED) {
    hipMemsetAsync(ws + OFF_CNT, 0x00, NBINS, stream);              // cnt = 0
    hipMemsetAsync(ws + OFF_GINX, 0xFF, NBINS * 4, stream);         // ginx = -1
    xconv_kernel<<<(N_VOX * 8 + 255) / 256, 256, 0, stream>>>(x, xb);
    build_kernel<<<(NPAIRS + 255) / 256, 256, 0, stream>>>(in_idx, out_idx,
                                                           cnt32, ginx, in1, ov, ctrs);
    scan_kernel<<<(NBINS / 4 + 255) / 256, 256, 0, stream>>>(cnt32, ginx, in1, list, ctrs);
    fixup_kernel<<<1024, 256, 0, stream>>>(xb, list, ctrs);
    conv_out_kernel<<<NPAD / 64, 256, 0, stream>>>(xb, wt, ginx, out);
    ov_kernel<<<1024, 256, 0, stream>>>(x, W, ov, ctrs, out);
  } else {
    hipMemsetAsync(d_out, 0, (size_t)N_VOX * C_OUTCH * sizeof(float), stream);
    conv_kernel<<<K3 * (M_PAIRS / 64), 256, 0, stream>>>(x, wt, in_idx, out_idx, out);
  }

  stats_kernel<<<512, 256, 0, stream>>>(out, stats);
  norm_kernel<<<(N_VOX * (C_OUTCH / 4) + 255) / 256, 256, 0, stream>>>(out, stats, gamma, beta);
}

// Round 5
// 266.668 us; speedup vs baseline: 5.4068x; 1.5806x over previous
//
#include <hip/hip_runtime.h>

// Sparse conv block, output-major + pre-summed bins (round 5):
//   rulebook inverted to per-(k,o) single gather index (multi-input bins
//   pre-summed into aux rows); conv = 1 row-gather + 8 MFMA per k with
//   W[k] staged in LDS (double-buffered, XOR-swizzled); empty bins map to a
//   zeroed row (branchless). BN stats pass -> BN+ReLU.    MI355X / gfx950.

#define N_VOX   100000
#define NPAD    100096                  // multiple of 64
#define C_INCH  64
#define C_OUTCH 64
#define K3      27
#define M_PAIRS 40000
#define NPAIRS  (K3 * M_PAIRS)          // 1,080,000
#define BN_EPS  1e-5f
#define NBINS   (K3 * NPAD)             // 2,702,592
#define AUXMAX  184320
#define AUXCAP  (AUXMAX - 1)            // last aux slot reserved as ZROW
#define ZROW    (N_VOX + AUXMAX - 1)    // zeroed gather row for empty bins
#define OVMAX   65536

// ---- workspace layout (bytes) — identical footprint to rounds 3/4 ----------
#define OFF_WT     0u
#define OFF_STATS  221184u
#define OFF_CTRS   221696u                      // [0]=auxcnt [1]=ovcnt
#define OFF_CNT    221760u                      // u8 cnt[NBINS] packed in u32
#define OFF_GINX   2924352u                     // int ginx[NBINS], -1 = empty
#define OFF_IN1    13734720u                    // int in1[NBINS]
#define OFF_LIST   24545088u                    // int2 list[AUXMAX]
#define OFF_OV     26019648u                    // int2 ov[OVMAX]
#define OFF_XB     26543936u                    // bf16 rows[N_VOX+AUXMAX][64]
#define WS_NEED    ((size_t)OFF_XB + (size_t)(N_VOX + AUXMAX) * 128u)

#define NB_WT 432                       // 27*4096/256
#define NB_XB 3125                      // ceil(N_VOX*8/256)

typedef __attribute__((ext_vector_type(8))) short bf16x8;
typedef __attribute__((ext_vector_type(4))) float f32x4;

__device__ __forceinline__ short f2bf(float f) {
  unsigned u = __builtin_bit_cast(unsigned, f);
  u += 0x7FFFu + ((u >> 16) & 1u);
  return (short)(u >> 16);
}
__device__ __forceinline__ float bf2f(short s) {
  unsigned u = ((unsigned)(unsigned short)s) << 16;
  return __builtin_bit_cast(float, u);
}

// ---- fused init: Wt relayout (bf16), x->bf16, zero ZROW ---------------------
__global__ __launch_bounds__(256) void init_kernel(const float* __restrict__ W,
                                                   const float* __restrict__ x,
                                                   short* __restrict__ wt,
                                                   short* __restrict__ xb) {
  int b = blockIdx.x, t = threadIdx.x;
  if (b < NB_WT) {
    int id = b * 256 + t;
    int k = id >> 12, rem = id & 4095, c = rem >> 6, i = rem & 63;
    wt[id] = f2bf(W[(k << 12) + (i << 6) + c]);     // wt[k][c][i]
  } else if (b < NB_WT + NB_XB) {
    int id = (b - NB_WT) * 256 + t;
    if (id < N_VOX * 8) {
      float4 lo = ((const float4*)x)[id * 2];
      float4 hi = ((const float4*)x)[id * 2 + 1];
      bf16x8 v;
      v[0] = f2bf(lo.x); v[1] = f2bf(lo.y); v[2] = f2bf(lo.z); v[3] = f2bf(lo.w);
      v[4] = f2bf(hi.x); v[5] = f2bf(hi.y); v[6] = f2bf(hi.z); v[7] = f2bf(hi.w);
      ((bf16x8*)xb)[id] = v;
    }
  } else {
    if (t < 8) {
      bf16x8 z = {0, 0, 0, 0, 0, 0, 0, 0};
      ((bf16x8*)(xb + (size_t)ZROW * 64))[t] = z;
    }
  }
}

// ---- invert rulebook: byte-packed counts; slot0->ginx, slot1->in1,
//      slot>=2 -> ov (block-aggregated counter) ------------------------------
__global__ __launch_bounds__(256) void build_kernel(const int* __restrict__ in_idx,
                                                    const int* __restrict__ out_idx,
                                                    unsigned* __restrict__ cnt32,
                                                    int* __restrict__ ginx,
                                                    int* __restrict__ in1,
                                                    int2* __restrict__ ov,
                                                    int* __restrict__ ctrs) {
  __shared__ int l_cnt, l_base;
  int t = threadIdx.x;
  if (t == 0) l_cnt = 0;
  __syncthreads();
  int id = blockIdx.x * 256 + t;
  int lpos = -1;
  int2 entry = make_int2(0, 0);
  if (id < NPAIRS) {
    int k  = id / M_PAIRS;
    int in = in_idx[id];
    int o  = out_idx[id];
    int b  = k * NPAD + o;
    unsigned sh   = (unsigned)(b & 3) * 8u;
    unsigned old  = atomicAdd(&cnt32[b >> 2], 1u << sh);
    unsigned slot = (old >> sh) & 0xFFu;
    if (slot == 0u)      ginx[b] = in;
    else if (slot == 1u) in1[b]  = in;
    else { lpos = atomicAdd(&l_cnt, 1); entry = make_int2((k << 17) | in, o); }
  }
  __syncthreads();
  if (t == 0) l_base = (l_cnt > 0) ? atomicAdd(&ctrs[1], l_cnt) : 0;
  __syncthreads();
  if (lpos >= 0) {
    int p = l_base + lpos;
    if (p < OVMAX) ov[p] = entry;
  }
}

// ---- scan: cnt>=2 bins get aux slot (block-aggregated allocation) -----------
__global__ __launch_bounds__(256) void scan_kernel(const unsigned* __restrict__ cnt32,
                                                   int* __restrict__ ginx,
                                                   const int* __restrict__ in1,
                                                   int2* __restrict__ list,
                                                   int* __restrict__ ctrs) {
  __shared__ int l_cnt, l_base;
  int t = threadIdx.x;
  if (t == 0) l_cnt = 0;
  __syncthreads();
  int w = blockIdx.x * 256 + t;                 // one u32 word = 4 bins
  unsigned c4 = (w < NBINS / 4) ? cnt32[w] : 0u;
  int lp[4];
  #pragma unroll
  for (int s = 0; s < 4; ++s) {
    unsigned c = (c4 >> (s * 8)) & 0xFFu;
    lp[s] = (c >= 2u) ? atomicAdd(&l_cnt, 1) : -1;
  }
  __syncthreads();
  if (t == 0) l_base = (l_cnt > 0) ? atomicAdd(&ctrs[0], l_cnt) : 0;
  __syncthreads();
  int base = l_base;
  #pragma unroll
  for (int s = 0; s < 4; ++s) {
    if (lp[s] >= 0) {
      int b   = w * 4 + s;
      int pos = base + lp[s];
      if (pos < AUXCAP) {
        list[pos] = make_int2(ginx[b], in1[b]);
        ginx[b]   = N_VOX + pos;
      }
    }
  }
}

// ---- fixup: xb[N_VOX+i] = xb[in0] + xb[in1] ---------------------------------
__global__ __launch_bounds__(256) void fixup_kernel(short* __restrict__ xb,
                                                    const int2* __restrict__ list,
                                                    const int* __restrict__ ctrs) {
  int n = ctrs[0]; if (n > AUXCAP) n = AUXCAP;
  int wid  = (blockIdx.x * 256 + threadIdx.x) >> 6;
  int lane = threadIdx.x & 63;
  int nw   = gridDim.x * 4;
  for (int i = wid; i < n; i += nw) {
    int2 p = list[i];
    float a = bf2f(xb[(size_t)p.x * 64 + lane]);
    float b = bf2f(xb[(size_t)p.y * 64 + lane]);
    xb[(size_t)(N_VOX + i) * 64 + lane] = f2bf(a + b);
  }
}

// ---- conv: wave owns 16 out rows; 1 gather + 8 MFMA per k; W[k] staged in
//      LDS (double-buffered, XOR-swizzled); branchless ZROW for empty bins ----
// A lane l: row=l&15, k-slots (l>>4)*8+j (+32);  B lane l: col=l&15, same slots.
// C/D: col=lane&15, row=(lane>>4)*4+reg  [rounds 1-4 proven].
// LDS swizzle: byte ^= ((byte>>3)&0x70) i.e. row(c)&7 -> byte bits 4-6.
__global__ __launch_bounds__(256) void conv_out_kernel(const short* __restrict__ xb,
                                                       const short* __restrict__ wt,
                                                       const int* __restrict__ ginx,
                                                       float* __restrict__ out) {
  __shared__ short lds[2 * 4096];               // 2 x 8 KB (double buffer)
  int t = threadIdx.x, wave = t >> 6, lane = t & 63;
  int g = lane >> 4, c0 = lane & 15, g8 = g * 8;
  int obase = blockIdx.x * 64 + wave * 16;
  int o = obase + c0;

  // per-lane swizzled read base (shorts): logical byte (c0*128 + g*16)
  int rb  = ((c0 * 128 + g * 16) ^ ((c0 & 7) << 4)) >> 1;
  // staging write base (shorts): thread t copies logical bytes [32t, 32t+32)
  int wb0 = ((t * 32) ^ (((t >> 2) & 7) << 4)) >> 1;

  f32x4 acc[4];
  #pragma unroll
  for (int n = 0; n < 4; ++n) { acc[n][0]=0.f; acc[n][1]=0.f; acc[n][2]=0.f; acc[n][3]=0.f; }

  // ---- prologue: stage k=0, prefetch rows k=0, idx k=1
  bf16x8 s0 = *(const bf16x8*)(wt + t * 16);
  bf16x8 s1 = *(const bf16x8*)(wt + t * 16 + 8);
  int i0 = ginx[o];        i0 = (i0 < 0) ? ZROW : i0;
  const short* xr0 = xb + (size_t)i0 * 64;
  bf16x8 a0c = *(const bf16x8*)(xr0 + g8);
  bf16x8 a1c = *(const bf16x8*)(xr0 + 32 + g8);
  int i1 = ginx[NPAD + o]; i1 = (i1 < 0) ? ZROW : i1;
  *(bf16x8*)&lds[wb0]     = s0;
  *(bf16x8*)&lds[wb0 ^ 8] = s1;
  __syncthreads();

  int buf = 0;
  for (int k = 0; k < K3; ++k) {
    // issue stage loads for k+1
    if (k + 1 < K3) {
      const short* wn = wt + (size_t)(k + 1) * 4096 + t * 16;
      s0 = *(const bf16x8*)(wn);
      s1 = *(const bf16x8*)(wn + 8);
    }
    // issue row gather for k+1 (unconditional; empty -> ZROW, L1-hot zero row)
    const short* xr = xb + (size_t)i1 * 64;
    bf16x8 a0n = *(const bf16x8*)(xr + g8);
    bf16x8 a1n = *(const bf16x8*)(xr + 32 + g8);
    // issue idx load for k+2
    int i2 = ZROW;
    if (k + 2 < K3) { int r = ginx[(size_t)(k + 2) * NPAD + o]; i2 = (r < 0) ? ZROW : r; }

    // compute k from LDS[buf]
    const short* lb = lds + buf * 4096;
    #pragma unroll
    for (int n = 0; n < 4; ++n) {
      bf16x8 b0 = *(const bf16x8*)&lb[rb + n * 1024];           // i = 0..31 slice
      bf16x8 b1 = *(const bf16x8*)&lb[(rb ^ 32) + n * 1024];    // i = 32..63 slice
      acc[n] = __builtin_amdgcn_mfma_f32_16x16x32_bf16(a0c, b0, acc[n], 0, 0, 0);
      acc[n] = __builtin_amdgcn_mfma_f32_16x16x32_bf16(a1c, b1, acc[n], 0, 0, 0);
    }
    // publish stage k+1 into LDS[buf^1]
    if (k + 1 < K3) {
      short* wd = lds + (buf ^ 1) * 4096;
      *(bf16x8*)&wd[wb0]     = s0;
      *(bf16x8*)&wd[wb0 ^ 8] = s1;
    }
    __syncthreads();
    a0c = a0n; a1c = a1n; i1 = i2; buf ^= 1;
  }

  int orow = obase + (g << 2);
  #pragma unroll
  for (int j = 0; j < 4; ++j) {
    int r = orow + j;
    if (r < N_VOX) {
      float* op = out + (size_t)r * 64 + c0;
      op[0]  = acc[0][j];
      op[16] = acc[1][j];
      op[32] = acc[2][j];
      op[48] = acc[3][j];
    }
  }
}

// ---- overflow extras (slot>=2): exact fp32 dot (coalesced W), atomic add ----
__global__ __launch_bounds__(256) void ov_kernel(const float* __restrict__ x,
                                                 const float* __restrict__ W,
                                                 const int2* __restrict__ ov,
                                                 const int* __restrict__ ctrs,
                                                 float* __restrict__ out) {
  int n = ctrs[1]; if (n > OVMAX) n = OVMAX;
  int wid  = (blockIdx.x * 256 + threadIdx.x) >> 6;
  int lane = threadIdx.x & 63;
  int nw   = gridDim.x * 4;
  for (int i = wid; i < n; i += nw) {
    int2 e = ov[i];
    int in = e.x & 0x1FFFF;
    int k  = e.x >> 17;
    int o  = e.y;
    const float* xr = x + (size_t)in * 64;
    const float* wp = W + (size_t)k * 4096 + lane;
    float d = 0.f;
    #pragma unroll 8
    for (int ii = 0; ii < 64; ++ii) d += xr[ii] * wp[ii * 64];
    unsafeAtomicAdd(&out[(size_t)o * 64 + lane], d);
  }
}

// ---- legacy fallback: scatter conv (if ws too small) ------------------------
__global__ __launch_bounds__(256) void conv_kernel(const float* __restrict__ x,
                                                   const short* __restrict__ wt,
                                                   const int* __restrict__ in_idx,
                                                   const int* __restrict__ out_idx,
                                                   float* __restrict__ out) {
  __shared__ int s_in[64];
  __shared__ int s_out[64];
  int bx = blockIdx.x;
  int k = bx / (M_PAIRS / 64), base = (bx % (M_PAIRS / 64)) * 64;
  int t = threadIdx.x;
  if (t < 64)       s_in[t]       = in_idx[k * M_PAIRS + base + t];
  else if (t < 128) s_out[t - 64] = out_idx[k * M_PAIRS + base + (t - 64)];
  __syncthreads();
  int wave = t >> 6, lane = t & 63, g = lane >> 4, c0 = lane & 15;
  const float* xrow = x + (size_t)s_in[(wave << 4) + c0] * C_INCH + g * 8;
  float4 a0lo = *(const float4*)(xrow);
  float4 a0hi = *(const float4*)(xrow + 4);
  float4 a1lo = *(const float4*)(xrow + 32);
  float4 a1hi = *(const float4*)(xrow + 36);
  bf16x8 a0, a1;
  a0[0]=f2bf(a0lo.x); a0[1]=f2bf(a0lo.y); a0[2]=f2bf(a0lo.z); a0[3]=f2bf(a0lo.w);
  a0[4]=f2bf(a0hi.x); a0[5]=f2bf(a0hi.y); a0[6]=f2bf(a0hi.z); a0[7]=f2bf(a0hi.w);
  a1[0]=f2bf(a1lo.x); a1[1]=f2bf(a1lo.y); a1[2]=f2bf(a1lo.z); a1[3]=f2bf(a1lo.w);
  a1[4]=f2bf(a1hi.x); a1[5]=f2bf(a1hi.y); a1[6]=f2bf(a1hi.z); a1[7]=f2bf(a1hi.w);
  const short* wtk = wt + k * 4096;
  f32x4 acc[4];
  #pragma unroll
  for (int n = 0; n < 4; ++n) { acc[n][0]=0.f; acc[n][1]=0.f; acc[n][2]=0.f; acc[n][3]=0.f; }
  #pragma unroll
  for (int n = 0; n < 4; ++n) {
    int c = n * 16 + c0;
    bf16x8 b0 = *(const bf16x8*)(wtk + c * 64 + g * 8);
    bf16x8 b1 = *(const bf16x8*)(wtk + c * 64 + 32 + g * 8);
    acc[n] = __builtin_amdgcn_mfma_f32_16x16x32_bf16(a0, b0, acc[n], 0, 0, 0);
    acc[n] = __builtin_amdgcn_mfma_f32_16x16x32_bf16(a1, b1, acc[n], 0, 0, 0);
  }
  int rbase = (wave << 4) + ((lane >> 4) << 2);
  #pragma unroll
  for (int j = 0; j < 4; ++j) {
    size_t o2 = (size_t)s_out[rbase + j] * C_OUTCH;
    #pragma unroll
    for (int n = 0; n < 4; ++n) unsafeAtomicAdd(&out[o2 + n * 16 + c0], acc[n][j]);
  }
}

// ---- per-channel sum / sum-of-squares --------------------------------------
__global__ __launch_bounds__(256) void stats_kernel(const float* __restrict__ out,
                                                    float* __restrict__ stats) {
  __shared__ float s1[256], s2[256];
  int t = threadIdx.x, c = t & 63, rsub = t >> 6;
  float sum1 = 0.f, sum2 = 0.f;
  for (int r = blockIdx.x * 4 + rsub; r < N_VOX; r += gridDim.x * 4) {
    float v = out[r * 64 + c];
    sum1 += v; sum2 += v * v;
  }
  s1[t] = sum1; s2[t] = sum2;
  __syncthreads();
  if (t < 64) {
    sum1 = s1[t] + s1[t + 64] + s1[t + 128] + s1[t + 192];
    sum2 = s2[t] + s2[t + 64] + s2[t + 128] + s2[t + 192];
    unsafeAtomicAdd(&stats[c], sum1);
    unsafeAtomicAdd(&stats[64 + c], sum2);
  }
}

// ---- finalize BN + ReLU in place -------------------------------------------
__global__ __launch_bounds__(256) void norm_kernel(float* __restrict__ out,
                                                   const float* __restrict__ stats,
                                                   const float* __restrict__ gamma,
                                                   const float* __restrict__ beta) {
  int i4 = blockIdx.x * 256 + threadIdx.x;
  if (i4 >= N_VOX * (C_OUTCH / 4)) return;
  const float invN = 1.0f / (float)N_VOX;
  float4 v = ((const float4*)out)[i4];
  int c0 = (i4 << 2) & 63;
  float r[4] = {v.x, v.y, v.z, v.w};
  #pragma unroll
  for (int j = 0; j < 4; ++j) {
    int c = c0 + j;
    float mean = stats[c] * invN;
    float ex2  = stats[64 + c] * invN;
    float var  = ex2 - mean * mean;
    float scale = gamma[c] * rsqrtf(var + BN_EPS);
    float shift = beta[c] - mean * scale;
    r[j] = fmaxf(r[j] * scale + shift, 0.0f);
  }
  v.x = r[0]; v.y = r[1]; v.z = r[2]; v.w = r[3];
  ((float4*)out)[i4] = v;
}

extern "C" void kernel_launch(void* const* d_in, const int* in_sizes, int n_in,
                              void* d_out, int out_size, void* d_ws, size_t ws_size,
                              hipStream_t stream) {
  const float* x      = (const float*)d_in[0];
  const float* W      = (const float*)d_in[1];
  const float* gamma  = (const float*)d_in[2];
  const float* beta   = (const float*)d_in[3];
  const int*   in_idx = (const int*)d_in[4];
  const int*   out_idx= (const int*)d_in[5];
  float* out = (float*)d_out;

  char* ws = (char*)d_ws;
  short*    wt    = (short*)(ws + OFF_WT);
  float*    stats = (float*)(ws + OFF_STATS);
  int*      ctrs  = (int*)(ws + OFF_CTRS);
  unsigned* cnt32 = (unsigned*)(ws + OFF_CNT);
  int*      ginx  = (int*)(ws + OFF_GINX);
  int*      in1   = (int*)(ws + OFF_IN1);
  int2*     list  = (int2*)(ws + OFF_LIST);
  int2*     ov    = (int2*)(ws + OFF_OV);
  short*    xb    = (short*)(ws + OFF_XB);

  hipMemsetAsync(ws + OFF_STATS, 0, OFF_CNT - OFF_STATS, stream);   // stats + ctrs

  if (ws_size >= WS_NEED) {
    hipMemsetAsync(ws + OFF_CNT, 0x00, NBINS, stream);              // cnt = 0
    hipMemsetAsync(ws + OFF_GINX, 0xFF, NBINS * 4, stream);         // ginx = -1
    init_kernel<<<NB_WT + NB_XB + 1, 256, 0, stream>>>(W, x, wt, xb);
    build_kernel<<<(NPAIRS + 255) / 256, 256, 0, stream>>>(in_idx, out_idx,
                                                           cnt32, ginx, in1, ov, ctrs);
    scan_kernel<<<(NBINS / 4 + 255) / 256, 256, 0, stream>>>(cnt32, ginx, in1, list, ctrs);
    fixup_kernel<<<2048, 256, 0, stream>>>(xb, list, ctrs);
    conv_out_kernel<<<NPAD / 64, 256, 0, stream>>>(xb, wt, ginx, out);
    ov_kernel<<<1024, 256, 0, stream>>>(x, W, ov, ctrs, out);
  } else {
    init_kernel<<<NB_WT + NB_XB + 1, 256, 0, stream>>>(W, x, wt, xb);
    hipMemsetAsync(d_out, 0, (size_t)N_VOX * C_OUTCH * sizeof(float), stream);
    conv_kernel<<<K3 * (M_PAIRS / 64), 256, 0, stream>>>(x, wt, in_idx, out_idx, out);
  }

  stats_kernel<<<512, 256, 0, stream>>>(out, stats);
  norm_kernel<<<(N_VOX * (C_OUTCH / 4) + 255) / 256, 256, 0, stream>>>(out, stats, gamma, beta);
}

// Round 6
// 218.570 us; speedup vs baseline: 6.5966x; 1.2201x over previous
//
#include <hip/hip_runtime.h>

// Sparse conv block, output-major, exch-chain inversion (round 6):
//   build: per pair ONE atomicExch into bing[k][o] + coalesced node write
//   compact: chains -> direct gather row (ZROW / single row / aux slot), in place
//   fixup: aux rows = bf16 sum of chain inputs (any count, no overflow path)
//   conv: 128 out rows/block, W[k] LDS double-buffered+swizzled, 1 gather set
//         + 16 MFMA per k per wave, fused BN stats
//   norm: BN+ReLU.                                MI355X / gfx950.

#define N_VOX   100000
#define NPAD    100096                  // multiple of 64
#define C_INCH  64
#define C_OUTCH 64
#define K3      27
#define M_PAIRS 40000
#define NPAIRS  (K3 * M_PAIRS)          // 1,080,000
#define BN_EPS  1e-5f
#define NBINS   (K3 * NPAD)             // 2,702,592
#define AUXMAX  184320                  // expected ~166k multi-input bins
#define AUXCAP  (AUXMAX - 1)
#define ZROW    (N_VOX + AUXMAX - 1)    // zeroed gather row (empty bins)

// ---- workspace layout (bytes), total 56,802,432 (< proven-fit 64.9 MB) ------
#define OFF_WT     0u                       // bf16 Wt[k][c][i]  (221,184)
#define OFF_STATS  221184u                  // f32[128]
#define OFF_CTRS   221696u                  // [0]=aux counter
#define OFF_BING   221760u                  // int bing[NBINS]: chain head -> gather row
#define OFF_NODE   11032128u                // int2 node[NPAIRS] = {nxt, in}
#define OFF_LIST   19672128u                // int list[AUXMAX] = chain head
#define OFF_XB     20409472u                // bf16 rows[N_VOX + AUXMAX][64]
#define WS_NEED    ((size_t)OFF_XB + (size_t)(N_VOX + AUXMAX) * 128u)

#define NB_WT 432                       // 27*4096/256
#define NB_XB 3125                      // ceil(N_VOX*8/256)

typedef __attribute__((ext_vector_type(8))) short bf16x8;
typedef __attribute__((ext_vector_type(4))) float f32x4;

__device__ __forceinline__ short f2bf(float f) {
  unsigned u = __builtin_bit_cast(unsigned, f);
  u += 0x7FFFu + ((u >> 16) & 1u);
  return (short)(u >> 16);
}
__device__ __forceinline__ float bf2f(short s) {
  unsigned u = ((unsigned)(unsigned short)s) << 16;
  return __builtin_bit_cast(float, u);
}

// ---- fused init: Wt relayout (bf16), x->bf16, zero ZROW ---------------------
__global__ __launch_bounds__(256) void init_kernel(const float* __restrict__ W,
                                                   const float* __restrict__ x,
                                                   short* __restrict__ wt,
                                                   short* __restrict__ xb) {
  int b = blockIdx.x, t = threadIdx.x;
  if (b < NB_WT) {
    int id = b * 256 + t;
    int k = id >> 12, rem = id & 4095, c = rem >> 6, i = rem & 63;
    wt[id] = f2bf(W[(k << 12) + (i << 6) + c]);     // wt[k][c][i]
  } else if (b < NB_WT + NB_XB) {
    int id = (b - NB_WT) * 256 + t;
    if (id < N_VOX * 8) {
      float4 lo = ((const float4*)x)[id * 2];
      float4 hi = ((const float4*)x)[id * 2 + 1];
      bf16x8 v;
      v[0] = f2bf(lo.x); v[1] = f2bf(lo.y); v[2] = f2bf(lo.z); v[3] = f2bf(lo.w);
      v[4] = f2bf(hi.x); v[5] = f2bf(hi.y); v[6] = f2bf(hi.z); v[7] = f2bf(hi.w);
      ((bf16x8*)xb)[id] = v;
    }
  } else {
    if (t < 8) {
      bf16x8 z = {0, 0, 0, 0, 0, 0, 0, 0};
      ((bf16x8*)(xb + (size_t)ZROW * 64))[t] = z;
    }
  }
}

// ---- build: branchless exch-chain. 1 scattered atomic + 1 coalesced store ---
__global__ __launch_bounds__(256) void build_kernel(const int* __restrict__ in_idx,
                                                    const int* __restrict__ out_idx,
                                                    int* __restrict__ bing,
                                                    int2* __restrict__ node) {
  int id = blockIdx.x * 256 + threadIdx.x;
  if (id >= NPAIRS) return;
  int k  = id / M_PAIRS;
  int in = in_idx[id];
  int o  = out_idx[id];
  int b  = k * NPAD + o;
  int old = atomicExch(&bing[b], id);
  node[id] = make_int2(old, in);
}

// ---- compact: chain head -> gather row, in place ----------------------------
//   empty (-1) -> ZROW ; len-1 -> input row ; len>=2 -> N_VOX + aux slot
__global__ __launch_bounds__(256) void compact_kernel(int* __restrict__ bing,
                                                      const int2* __restrict__ node,
                                                      int* __restrict__ list,
                                                      int* __restrict__ ctrs) {
  __shared__ int l_cnt, l_base;
  int t = threadIdx.x;
  if (t == 0) l_cnt = 0;
  __syncthreads();
  int w = blockIdx.x * 256 + t;                 // one int4 = 4 bins
  bool ok = (w < NBINS / 4);
  int4 h4 = ok ? ((int4*)bing)[w] : make_int4(-1, -1, -1, -1);
  int hv[4] = {h4.x, h4.y, h4.z, h4.w};
  int gv[4];
  int lp[4];
  int2 n0[4];
  #pragma unroll
  for (int s = 0; s < 4; ++s) {
    lp[s] = -1;
    if (hv[s] < 0) { gv[s] = ZROW; }
    else {
      n0[s] = node[hv[s]];                      // scattered 8B read
      if (n0[s].x < 0) gv[s] = n0[s].y;         // single input
      else             lp[s] = atomicAdd(&l_cnt, 1);
    }
  }
  __syncthreads();
  if (t == 0) l_base = (l_cnt > 0) ? atomicAdd(&ctrs[0], l_cnt) : 0;
  __syncthreads();
  #pragma unroll
  for (int s = 0; s < 4; ++s) {
    if (lp[s] >= 0) {
      int pos = l_base + lp[s];
      if (pos < AUXCAP) { list[pos] = hv[s]; gv[s] = N_VOX + pos; }
      else              { gv[s] = n0[s].y; }    // overflow guard (won't hit)
    }
  }
  if (ok) ((int4*)bing)[w] = make_int4(gv[0], gv[1], gv[2], gv[3]);
}

// ---- fixup: aux row = sum of chain's input rows (bf16 in, f32 acc) ----------
__global__ __launch_bounds__(256) void fixup_kernel(short* __restrict__ xb,
                                                    const int* __restrict__ list,
                                                    const int2* __restrict__ node,
                                                    const int* __restrict__ ctrs) {
  int n = ctrs[0]; if (n > AUXCAP) n = AUXCAP;
  int wid  = (blockIdx.x * 256 + threadIdx.x) >> 6;
  int lane = threadIdx.x & 63;
  int nw   = gridDim.x * 4;
  for (int i = wid; i < n; i += nw) {
    int h = list[i];
    float acc = 0.f;
    while (h >= 0) {
      int2 nd = node[h];                        // broadcast (uniform per wave)
      acc += bf2f(xb[(size_t)nd.y * 64 + lane]);
      h = nd.x;
    }
    xb[(size_t)(N_VOX + i) * 64 + lane] = f2bf(acc);
  }
}

// ---- conv: block owns 128 out rows (32/wave); per k: 4 gathers + 16 MFMA;
//      W[k] LDS double-buffered + XOR-swizzled; fused BN stats ----------------
// A lane l: row=l&15, k-slots (l>>4)*8+j (+32);  B lane l: col=l&15, same slots.
// C/D: col=lane&15, row=(lane>>4)*4+reg  [rounds 1-5 proven].
// LDS swizzle: logical byte ^= ((row c)&7)<<4  [round-5 proven].
__global__ __launch_bounds__(256) void conv_out_kernel(const short* __restrict__ xb,
                                                       const short* __restrict__ wt,
                                                       const int* __restrict__ bing,
                                                       float* __restrict__ out,
                                                       float* __restrict__ stats) {
  __shared__ short lds[2 * 4096];               // 2 x 8 KB W double buffer
  __shared__ float ls[128];
  int t = threadIdx.x, wave = t >> 6, lane = t & 63;
  int g = lane >> 4, c0 = lane & 15, g8 = g * 8;
  int o0 = blockIdx.x * 128 + wave * 32 + c0;   // rows 0..15 of this wave
  int o1 = o0 + 16;                             // rows 16..31

  int rb  = ((c0 * 128 + g * 16) ^ ((c0 & 7) << 4)) >> 1;
  int wb0 = ((t * 32) ^ (((t >> 2) & 7) << 4)) >> 1;
  if (t < 128) ls[t] = 0.f;

  f32x4 acc0[4], acc1[4];
  #pragma unroll
  for (int n = 0; n < 4; ++n) {
    acc0[n][0]=0.f; acc0[n][1]=0.f; acc0[n][2]=0.f; acc0[n][3]=0.f;
    acc1[n][0]=0.f; acc1[n][1]=0.f; acc1[n][2]=0.f; acc1[n][3]=0.f;
  }

  // prologue: stage W0, gather k=0 rows, idx k=1
  bf16x8 s0w = *(const bf16x8*)(wt + t * 16);
  bf16x8 s1w = *(const bf16x8*)(wt + t * 16 + 8);
  int ia = bing[o0], ib = bing[o1];
  const short* xa = xb + (size_t)ia * 64;
  const short* xc = xb + (size_t)ib * 64;
  bf16x8 a0c = *(const bf16x8*)(xa + g8);
  bf16x8 a1c = *(const bf16x8*)(xa + 32 + g8);
  bf16x8 a2c = *(const bf16x8*)(xc + g8);
  bf16x8 a3c = *(const bf16x8*)(xc + 32 + g8);
  int i1a = bing[NPAD + o0], i1b = bing[NPAD + o1];
  *(bf16x8*)&lds[wb0]     = s0w;
  *(bf16x8*)&lds[wb0 ^ 8] = s1w;
  __syncthreads();

  int buf = 0;
  for (int k = 0; k < K3; ++k) {
    if (k + 1 < K3) {                           // W stage loads for k+1
      const short* wn = wt + (size_t)(k + 1) * 4096 + t * 16;
      s0w = *(const bf16x8*)(wn);
      s1w = *(const bf16x8*)(wn + 8);
    }
    // gather rows for k+1 (branchless: indices always valid, empty -> ZROW)
    const short* pa = xb + (size_t)i1a * 64;
    const short* pb = xb + (size_t)i1b * 64;
    bf16x8 a0n = *(const bf16x8*)(pa + g8);
    bf16x8 a1n = *(const bf16x8*)(pa + 32 + g8);
    bf16x8 a2n = *(const bf16x8*)(pb + g8);
    bf16x8 a3n = *(const bf16x8*)(pb + 32 + g8);
    int i2a = ZROW, i2b = ZROW;
    if (k + 2 < K3) {
      i2a = bing[(size_t)(k + 2) * NPAD + o0];
      i2b = bing[(size_t)(k + 2) * NPAD + o1];
    }
    // compute k from lds[buf]
    const short* lb = lds + buf * 4096;
    #pragma unroll
    for (int n = 0; n < 4; ++n) {
      bf16x8 b0 = *(const bf16x8*)&lb[rb + n * 1024];
      bf16x8 b1 = *(const bf16x8*)&lb[(rb ^ 32) + n * 1024];
      acc0[n] = __builtin_amdgcn_mfma_f32_16x16x32_bf16(a0c, b0, acc0[n], 0, 0, 0);
      acc0[n] = __builtin_amdgcn_mfma_f32_16x16x32_bf16(a1c, b1, acc0[n], 0, 0, 0);
      acc1[n] = __builtin_amdgcn_mfma_f32_16x16x32_bf16(a2c, b0, acc1[n], 0, 0, 0);
      acc1[n] = __builtin_amdgcn_mfma_f32_16x16x32_bf16(a3c, b1, acc1[n], 0, 0, 0);
    }
    if (k + 1 < K3) {                           // publish W k+1
      short* wd = lds + (buf ^ 1) * 4096;
      *(bf16x8*)&wd[wb0]     = s0w;
      *(bf16x8*)&wd[wb0 ^ 8] = s1w;
    }
    __syncthreads();
    a0c = a0n; a1c = a1n; a2c = a2n; a3c = a3n;
    i1a = i2a; i1b = i2b; buf ^= 1;
  }

  // store: each out row exactly once
  int orow = blockIdx.x * 128 + wave * 32 + (g << 2);
  #pragma unroll
  for (int j = 0; j < 4; ++j) {
    int r0 = orow + j, r1 = orow + 16 + j;
    if (r0 < N_VOX) {
      float* op = out + (size_t)r0 * 64 + c0;
      op[0] = acc0[0][j]; op[16] = acc0[1][j]; op[32] = acc0[2][j]; op[48] = acc0[3][j];
    }
    if (r1 < N_VOX) {
      float* op = out + (size_t)r1 * 64 + c0;
      op[0] = acc1[0][j]; op[16] = acc1[1][j]; op[32] = acc1[2][j]; op[48] = acc1[3][j];
    }
  }

  // fused BN stats (padding rows are exact zeros -> contribute nothing)
  #pragma unroll
  for (int n = 0; n < 4; ++n) {
    float s = 0.f, q = 0.f;
    #pragma unroll
    for (int j = 0; j < 4; ++j) {
      float v0 = acc0[n][j], v1 = acc1[n][j];
      s += v0 + v1; q += v0 * v0 + v1 * v1;
    }
    atomicAdd(&ls[n * 16 + c0], s);
    atomicAdd(&ls[64 + n * 16 + c0], q);
  }
  __syncthreads();
  if (t < 128) unsafeAtomicAdd(&stats[t], ls[t]);
}

// ---- legacy fallback: scatter conv + stats (if ws too small) ----------------
__global__ __launch_bounds__(256) void conv_kernel(const float* __restrict__ x,
                                                   const short* __restrict__ wt,
                                                   const int* __restrict__ in_idx,
                                                   const int* __restrict__ out_idx,
                                                   float* __restrict__ out) {
  __shared__ int s_in[64];
  __shared__ int s_out[64];
  int bx = blockIdx.x;
  int k = bx / (M_PAIRS / 64), base = (bx % (M_PAIRS / 64)) * 64;
  int t = threadIdx.x;
  if (t < 64)       s_in[t]       = in_idx[k * M_PAIRS + base + t];
  else if (t < 128) s_out[t - 64] = out_idx[k * M_PAIRS + base + (t - 64)];
  __syncthreads();
  int wave = t >> 6, lane = t & 63, g = lane >> 4, c0 = lane & 15;
  const float* xrow = x + (size_t)s_in[(wave << 4) + c0] * C_INCH + g * 8;
  float4 a0lo = *(const float4*)(xrow);
  float4 a0hi = *(const float4*)(xrow + 4);
  float4 a1lo = *(const float4*)(xrow + 32);
  float4 a1hi = *(const float4*)(xrow + 36);
  bf16x8 a0, a1;
  a0[0]=f2bf(a0lo.x); a0[1]=f2bf(a0lo.y); a0[2]=f2bf(a0lo.z); a0[3]=f2bf(a0lo.w);
  a0[4]=f2bf(a0hi.x); a0[5]=f2bf(a0hi.y); a0[6]=f2bf(a0hi.z); a0[7]=f2bf(a0hi.w);
  a1[0]=f2bf(a1lo.x); a1[1]=f2bf(a1lo.y); a1[2]=f2bf(a1lo.z); a1[3]=f2bf(a1lo.w);
  a1[4]=f2bf(a1hi.x); a1[5]=f2bf(a1hi.y); a1[6]=f2bf(a1hi.z); a1[7]=f2bf(a1hi.w);
  const short* wtk = wt + k * 4096;
  f32x4 acc[4];
  #pragma unroll
  for (int n = 0; n < 4; ++n) { acc[n][0]=0.f; acc[n][1]=0.f; acc[n][2]=0.f; acc[n][3]=0.f; }
  #pragma unroll
  for (int n = 0; n < 4; ++n) {
    int c = n * 16 + c0;
    bf16x8 b0 = *(const bf16x8*)(wtk + c * 64 + g * 8);
    bf16x8 b1 = *(const bf16x8*)(wtk + c * 64 + 32 + g * 8);
    acc[n] = __builtin_amdgcn_mfma_f32_16x16x32_bf16(a0, b0, acc[n], 0, 0, 0);
    acc[n] = __builtin_amdgcn_mfma_f32_16x16x32_bf16(a1, b1, acc[n], 0, 0, 0);
  }
  int rbase = (wave << 4) + ((lane >> 4) << 2);
  #pragma unroll
  for (int j = 0; j < 4; ++j) {
    size_t o2 = (size_t)s_out[rbase + j] * C_OUTCH;
    #pragma unroll
    for (int n = 0; n < 4; ++n) unsafeAtomicAdd(&out[o2 + n * 16 + c0], acc[n][j]);
  }
}

__global__ __launch_bounds__(256) void stats_kernel(const float* __restrict__ out,
                                                    float* __restrict__ stats) {
  __shared__ float s1[256], s2[256];
  int t = threadIdx.x, c = t & 63, rsub = t >> 6;
  float sum1 = 0.f, sum2 = 0.f;
  for (int r = blockIdx.x * 4 + rsub; r < N_VOX; r += gridDim.x * 4) {
    float v = out[r * 64 + c];
    sum1 += v; sum2 += v * v;
  }
  s1[t] = sum1; s2[t] = sum2;
  __syncthreads();
  if (t < 64) {
    sum1 = s1[t] + s1[t + 64] + s1[t + 128] + s1[t + 192];
    sum2 = s2[t] + s2[t + 64] + s2[t + 128] + s2[t + 192];
    unsafeAtomicAdd(&stats[c], sum1);
    unsafeAtomicAdd(&stats[64 + c], sum2);
  }
}

// ---- finalize BN + ReLU in place -------------------------------------------
__global__ __launch_bounds__(256) void norm_kernel(float* __restrict__ out,
                                                   const float* __restrict__ stats,
                                                   const float* __restrict__ gamma,
                                                   const float* __restrict__ beta) {
  int i4 = blockIdx.x * 256 + threadIdx.x;
  if (i4 >= N_VOX * (C_OUTCH / 4)) return;
  const float invN = 1.0f / (float)N_VOX;
  float4 v = ((const float4*)out)[i4];
  int c0 = (i4 << 2) & 63;
  float r[4] = {v.x, v.y, v.z, v.w};
  #pragma unroll
  for (int j = 0; j < 4; ++j) {
    int c = c0 + j;
    float mean = stats[c] * invN;
    float ex2  = stats[64 + c] * invN;
    float var  = ex2 - mean * mean;
    float scale = gamma[c] * rsqrtf(var + BN_EPS);
    float shift = beta[c] - mean * scale;
    r[j] = fmaxf(r[j] * scale + shift, 0.0f);
  }
  v.x = r[0]; v.y = r[1]; v.z = r[2]; v.w = r[3];
  ((float4*)out)[i4] = v;
}

extern "C" void kernel_launch(void* const* d_in, const int* in_sizes, int n_in,
                              void* d_out, int out_size, void* d_ws, size_t ws_size,
                              hipStream_t stream) {
  const float* x      = (const float*)d_in[0];
  const float* W      = (const float*)d_in[1];
  const float* gamma  = (const float*)d_in[2];
  const float* beta   = (const float*)d_in[3];
  const int*   in_idx = (const int*)d_in[4];
  const int*   out_idx= (const int*)d_in[5];
  float* out = (float*)d_out;

  char* ws = (char*)d_ws;
  short* wt    = (short*)(ws + OFF_WT);
  float* stats = (float*)(ws + OFF_STATS);
  int*   ctrs  = (int*)(ws + OFF_CTRS);
  int*   bing  = (int*)(ws + OFF_BING);
  int2*  node  = (int2*)(ws + OFF_NODE);
  int*   list  = (int*)(ws + OFF_LIST);
  short* xb    = (short*)(ws + OFF_XB);

  hipMemsetAsync(ws + OFF_STATS, 0, OFF_BING - OFF_STATS, stream);  // stats+ctrs

  if (ws_size >= WS_NEED) {
    hipMemsetAsync(ws + OFF_BING, 0xFF, NBINS * 4, stream);         // heads = -1
    init_kernel<<<NB_WT + NB_XB + 1, 256, 0, stream>>>(W, x, wt, xb);
    build_kernel<<<(NPAIRS + 255) / 256, 256, 0, stream>>>(in_idx, out_idx, bing, node);
    compact_kernel<<<(NBINS / 4 + 255) / 256, 256, 0, stream>>>(bing, node, list, ctrs);
    fixup_kernel<<<2048, 256, 0, stream>>>(xb, list, node, ctrs);
    conv_out_kernel<<<NPAD / 128, 256, 0, stream>>>(xb, wt, bing, out, stats);
  } else {
    init_kernel<<<NB_WT + NB_XB + 1, 256, 0, stream>>>(W, x, wt, xb);
    hipMemsetAsync(d_out, 0, (size_t)N_VOX * C_OUTCH * sizeof(float), stream);
    conv_kernel<<<K3 * (M_PAIRS / 64), 256, 0, stream>>>(x, wt, in_idx, out_idx, out);
    stats_kernel<<<512, 256, 0, stream>>>(out, stats);
  }

  norm_kernel<<<(N_VOX * (C_OUTCH / 4) + 255) / 256, 256, 0, stream>>>(out, stats, gamma, beta);
}